// Round 23
// baseline (78.217 us; speedup 1.0000x reference)
//
#include <hip/hip_runtime.h>
#include <math.h>

#define DD 128
#define SLOT 64   // fixed CSR bucket stride; deg~Poisson(12.8), P(>64) ~ 0

typedef short bf16x8 __attribute__((ext_vector_type(8)));
typedef float f32x4  __attribute__((ext_vector_type(4)));

__device__ __forceinline__ unsigned bf16rne(float f) {
    unsigned u = __float_as_uint(f);
    return (u + 0x7FFFu + ((u >> 16) & 1u)) >> 16;
}
__device__ __forceinline__ float2 bf2f(unsigned u) {
    float2 r;
    r.x = __uint_as_float(u << 16);
    r.y = __uint_as_float(u & 0xFFFF0000u);
    return r;
}
__device__ __forceinline__ float gelu1(float v) {
    return 0.5f * v * (1.f + erff(v * 0.70710678118654752f));
}

// ---- tiny zero: conv1 cnt region + mb + nLive (~2.7k ints) ------------------
__global__ __launch_bounds__(256) void k_zero2(int* __restrict__ p, int T) {
    int stride = gridDim.x * 256;
    for (int i = blockIdx.x * 256 + threadIdx.x; i < T; i += stride) p[i] = 0;
}

// ---- mark: [0,gZ) zero cnt[0..N) || conv1 hist/fill + livelist + w pack ----
__global__ __launch_bounds__(256) void k_mark(const int* __restrict__ src1,
                                              const int* __restrict__ dst1,
                                              int E1, int BS,
                                              unsigned* __restrict__ mb,
                                              int* __restrict__ livelist,
                                              int* __restrict__ nLive,
                                              int* __restrict__ cnt,
                                              int* __restrict__ ssrc, int N,
                                              const float* __restrict__ w0,
                                              const float* __restrict__ w1,
                                              unsigned short* __restrict__ wp0,
                                              unsigned short* __restrict__ wp1,
                                              int gZ) {
    if (blockIdx.x < gZ) {                    // zero cnt[0..N) for fill0
        int stride = gZ * 256;
        for (int i = blockIdx.x * 256 + threadIdx.x; i < N; i += stride)
            cnt[i] = 0;
        return;
    }
    __shared__ int lbuf[1280];
    __shared__ int lcnt, lbase;
    if (threadIdx.x == 0) lcnt = 0;
    __syncthreads();

    int role = blockIdx.x - gZ;
    int idx = role * 256 + threadIdx.x;
    if (idx < 2 * DD * DD) {
        const float* w = (idx < DD * DD) ? w0 : w1;
        unsigned short* wp = (idx < DD * DD) ? wp0 : wp1;
        int i = idx & (DD * DD - 1);
        int k = i >> 7, c = i & 127;
        int nt = c >> 4, ks = k >> 5;
        int lane = (c & 15) | (((k >> 3) & 3) << 4);
        wp[(((nt * 4 + ks) * 64) + lane) * 8 + (k & 7)] =
            (unsigned short)bf16rne(w[k * DD + c]);
    }

    int base = role * 1024 + threadIdx.x;
    #pragma unroll
    for (int j = 0; j < 4; ++j) {
        int e = base + j * 256;
        if (e < E1) {
            int d = dst1[e];
            if (d < BS) {
                int s = src1[e];
                int r = atomicAdd(&cnt[N + d], 1);
                if (r < SLOT) ssrc[(size_t)(N + d) * SLOT + r] = s;
                unsigned old = atomicOr(&mb[s >> 5], 1u << (s & 31));
                if (!((old >> (s & 31)) & 1u))
                    lbuf[atomicAdd(&lcnt, 1)] = s;
            }
        }
    }
    int g = role * 256 + threadIdx.x;
    if (g < BS) {
        unsigned old = atomicOr(&mb[g >> 5], 1u << (g & 31));
        if (!((old >> (g & 31)) & 1u))
            lbuf[atomicAdd(&lcnt, 1)] = g;
    }
    __syncthreads();
    if (threadIdx.x == 0) lbase = atomicAdd(nLive, lcnt);  // ONE global atomic
    __syncthreads();
    for (int i = threadIdx.x; i < lcnt; i += 256) livelist[lbase + i] = lbuf[i];
}

// ---- F1: MFMA linear0 (x loads issued BEFORE wl stage+barrier) || fill0 ----
__global__ __launch_bounds__(256) void k_hflin(
        const float* __restrict__ x, const unsigned short* __restrict__ wp,
        const float* __restrict__ b, unsigned* __restrict__ y, int nrows,
        int gLin,
        const int* __restrict__ src0, const int* __restrict__ dst0, int E0,
        const unsigned* __restrict__ mb, int* __restrict__ cnt,
        int* __restrict__ ssrc) {
    __shared__ bf16x8 wl[2048];   // 32 KB packed weights

    if (blockIdx.x >= gLin) {     // conv0 hist+fill (live dst only)
        int role = blockIdx.x - gLin;
        int base = role * 1024 + threadIdx.x;
        #pragma unroll
        for (int j = 0; j < 4; ++j) {
            int e = base + j * 256;
            if (e < E0) {
                int d = dst0[e];
                if ((mb[d >> 5] >> (d & 31)) & 1u) {
                    int r = atomicAdd(&cnt[d], 1);
                    if (r < SLOT) ssrc[(size_t)d * SLOT + r] = src0[e];
                }
            }
        }
        return;
    }

    int wave = threadIdx.x >> 6;
    int rb = blockIdx.x * 64 + wave * 16;
    int lane = threadIdx.x & 63;
    int c = lane & 15, g = lane >> 4;
    int rIn = rb + c;
    int rowValid = rIn < nrows;

    // issue full row slice FIRST: 8 independent loads in flight during the
    // weight staging + barrier below (latency hidden under ~300+ cycles)
    float xr[32];
    if (rowValid) {
        const float4* xp = (const float4*)&x[(size_t)rIn * DD];
        #pragma unroll
        for (int ks = 0; ks < 4; ++ks) {
            *(float4*)&xr[ks * 8]     = xp[ks * 8 + g * 2];
            *(float4*)&xr[ks * 8 + 4] = xp[ks * 8 + g * 2 + 1];
        }
    } else {
        #pragma unroll
        for (int j = 0; j < 32; ++j) xr[j] = 0.f;
    }

    const bf16x8* wg = (const bf16x8*)wp;
    #pragma unroll
    for (int i = 0; i < 8; ++i)
        wl[threadIdx.x + i * 256] = wg[threadIdx.x + i * 256];
    __syncthreads();

    f32x4 acc[8];
    #pragma unroll
    for (int nt = 0; nt < 8; ++nt) {
        float bb = b[nt * 16 + c];
        acc[nt] = (f32x4){bb, bb, bb, bb};
    }
    #pragma unroll
    for (int ks = 0; ks < 4; ++ks) {
        union { unsigned u[4]; bf16x8 v; } af;
        #pragma unroll
        for (int j = 0; j < 4; ++j)
            af.u[j] = bf16rne(xr[ks * 8 + 2 * j]) |
                      (bf16rne(xr[ks * 8 + 2 * j + 1]) << 16);
        #pragma unroll
        for (int nt = 0; nt < 8; ++nt)
            acc[nt] = __builtin_amdgcn_mfma_f32_16x16x32_bf16(
                af.v, wl[(nt * 4 + ks) * 64 + lane], acc[nt], 0, 0, 0);
    }
    int g4 = g * 4;
    #pragma unroll
    for (int nt = 0; nt < 8; ++nt) {
        #pragma unroll
        for (int reg = 0; reg < 4; ++reg) {
            unsigned u = bf16rne(acc[nt][reg]);
            unsigned up = (unsigned)__shfl_xor((int)u, 1, 64);
            int row = rb + g4 + reg;
            if (!(c & 1) && row < nrows)
                y[(size_t)row * 64 + (nt * 16 + c) / 2] = u | (up << 16);
        }
    }
}

// ---- agg0: livelist-driven, 4-edge pipeline; epilogue GELU+bf16 -> xg ------
__global__ __launch_bounds__(256) void k_aggL(const unsigned* __restrict__ xl,
                                              const int* __restrict__ cnt,
                                              const int* __restrict__ ssrc,
                                              const float* __restrict__ att,
                                              const float* __restrict__ bias,
                                              unsigned* __restrict__ xg,
                                              const int* __restrict__ livelist,
                                              const int* __restrict__ nLive) {
    int li = blockIdx.x * 4 + (threadIdx.x >> 6);
    if (li >= *nLive) return;
    int node = __builtin_amdgcn_readfirstlane(livelist[li]);
    int lane = threadIdx.x & 63;
    float2 attv = *(const float2*)&att[lane * 2];
    float2 xd = bf2f(xl[(size_t)node * 64 + lane]);
    int rs  = node * SLOT;
    int deg = cnt[node];
    deg = deg > SLOT ? SLOT : deg;

    float m = -3.4e38f, den = 0.f, accx = 0.f, accy = 0.f;
    int sA = (deg > 0) ? ssrc[rs]     : 0;
    int sB = (deg > 1) ? ssrc[rs + 1] : 0;
    int sC = (deg > 2) ? ssrc[rs + 2] : 0;
    int sD = (deg > 3) ? ssrc[rs + 3] : 0;
    unsigned uA = xl[(size_t)sA * 64 + lane];
    unsigned uB = xl[(size_t)sB * 64 + lane];
    unsigned uC = xl[(size_t)sC * 64 + lane];
    unsigned uD = xl[(size_t)sD * 64 + lane];

    int k = 0;
    for (; k + 3 < deg; k += 4) {
        int sE = (k + 4 < deg) ? ssrc[rs + k + 4] : 0;
        int sF = (k + 5 < deg) ? ssrc[rs + k + 5] : 0;
        int sG = (k + 6 < deg) ? ssrc[rs + k + 6] : 0;
        int sH = (k + 7 < deg) ? ssrc[rs + k + 7] : 0;
        unsigned uE = xl[(size_t)sE * 64 + lane];
        unsigned uF = xl[(size_t)sF * 64 + lane];
        unsigned uG = xl[(size_t)sG * 64 + lane];
        unsigned uH = xl[(size_t)sH * 64 + lane];
        float2 vA = bf2f(uA), vB = bf2f(uB), vC = bf2f(uC), vD = bf2f(uD);

        float t0x = xd.x + vA.x, t0y = xd.y + vA.y;
        t0x = t0x > 0.f ? t0x : 0.2f * t0x;
        t0y = t0y > 0.f ? t0y : 0.2f * t0y;
        float l0 = t0x * attv.x + t0y * attv.y;
        float t1x = xd.x + vB.x, t1y = xd.y + vB.y;
        t1x = t1x > 0.f ? t1x : 0.2f * t1x;
        t1y = t1y > 0.f ? t1y : 0.2f * t1y;
        float l1 = t1x * attv.x + t1y * attv.y;
        float t2x = xd.x + vC.x, t2y = xd.y + vC.y;
        t2x = t2x > 0.f ? t2x : 0.2f * t2x;
        t2y = t2y > 0.f ? t2y : 0.2f * t2y;
        float l2 = t2x * attv.x + t2y * attv.y;
        float t3x = xd.x + vD.x, t3y = xd.y + vD.y;
        t3x = t3x > 0.f ? t3x : 0.2f * t3x;
        t3y = t3y > 0.f ? t3y : 0.2f * t3y;
        float l3 = t3x * attv.x + t3y * attv.y;
        #pragma unroll
        for (int o = 8; o; o >>= 1) {
            l0 += __shfl_xor(l0, o, 64);
            l1 += __shfl_xor(l1, o, 64);
            l2 += __shfl_xor(l2, o, 64);
            l3 += __shfl_xor(l3, o, 64);
        }
        float mn = fmaxf(fmaxf(fmaxf(m, l0), fmaxf(l1, l2)), l3);
        float corr = __expf(m - mn);
        float w0 = __expf(l0 - mn);
        float w1 = __expf(l1 - mn);
        float w2 = __expf(l2 - mn);
        float w3 = __expf(l3 - mn);
        den  = den  * corr + w0 + w1 + w2 + w3;
        accx = accx * corr + w0 * vA.x + w1 * vB.x + w2 * vC.x + w3 * vD.x;
        accy = accy * corr + w0 * vA.y + w1 * vB.y + w2 * vC.y + w3 * vD.y;
        m = mn;
        sA = sE; sB = sF; sC = sG; sD = sH;
        uA = uE; uB = uF; uC = uG; uD = uH;
    }
    for (; k < deg; ++k) {      // 0-3 tail edges, rotate through uA
        float2 vA = bf2f(uA);
        float tx = xd.x + vA.x, ty = xd.y + vA.y;
        tx = tx > 0.f ? tx : 0.2f * tx;
        ty = ty > 0.f ? ty : 0.2f * ty;
        float l0 = tx * attv.x + ty * attv.y;
        #pragma unroll
        for (int o = 8; o; o >>= 1) l0 += __shfl_xor(l0, o, 64);
        float mn = fmaxf(m, l0);
        float corr = __expf(m - mn);
        float w0 = __expf(l0 - mn);
        den  = den  * corr + w0;
        accx = accx * corr + w0 * vA.x;
        accy = accy * corr + w0 * vA.y;
        m = mn;
        uA = uB; uB = uC; uC = uD;
    }

    float inv = (deg > 0) ? 1.f / den : 0.f;
    float gx = gelu1(accx * inv + bias[lane * 2]);
    float gy = gelu1(accy * inv + bias[lane * 2 + 1]);
    xg[(size_t)node * 64 + lane] = bf16rne(gx) | (bf16rne(gy) << 16);
}

// ---- lin1 over livelist rows: MFMA, A-fragments loaded as packed bf16 ------
__global__ __launch_bounds__(256) void k_linC(const unsigned* __restrict__ xg,
                                              const unsigned short* __restrict__ wp,
                                              const float* __restrict__ b,
                                              unsigned* __restrict__ y,
                                              const int* __restrict__ livelist,
                                              const int* __restrict__ nLive) {
    __shared__ bf16x8 wl[2048];   // 32 KB
    int nL = *nLive;
    if (blockIdx.x * 64 >= nL) return;

    int wave = threadIdx.x >> 6;
    int lb = blockIdx.x * 64 + wave * 16;
    int lane = threadIdx.x & 63;
    int c = lane & 15, g = lane >> 4;
    int liIn = lb + c;
    int rIn = (liIn < nL) ? livelist[liIn] : 0;
    const uint4* xp = (const uint4*)&xg[(size_t)rIn * 64];

    // issue A-fragment loads before wl stage (latency under barrier)
    uint4 aq[4];
    #pragma unroll
    for (int ks = 0; ks < 4; ++ks)
        aq[ks] = (liIn < nL) ? xp[ks * 4 + g] : make_uint4(0, 0, 0, 0);

    const bf16x8* wg = (const bf16x8*)wp;
    #pragma unroll
    for (int i = 0; i < 8; ++i)
        wl[threadIdx.x + i * 256] = wg[threadIdx.x + i * 256];
    __syncthreads();

    f32x4 acc[8];
    #pragma unroll
    for (int nt = 0; nt < 8; ++nt) {
        float bb = b[nt * 16 + c];
        acc[nt] = (f32x4){bb, bb, bb, bb};
    }
    #pragma unroll
    for (int ks = 0; ks < 4; ++ks) {
        union { uint4 q; bf16x8 v; } af;
        af.q = aq[ks];
        #pragma unroll
        for (int nt = 0; nt < 8; ++nt)
            acc[nt] = __builtin_amdgcn_mfma_f32_16x16x32_bf16(
                af.v, wl[(nt * 4 + ks) * 64 + lane], acc[nt], 0, 0, 0);
    }
    int g4 = g * 4;
    #pragma unroll
    for (int reg = 0; reg < 4; ++reg) {
        int liOut = lb + g4 + reg;
        int row = (liOut < nL) ? livelist[liOut] : -1;
        #pragma unroll
        for (int nt = 0; nt < 8; ++nt) {
            unsigned u = bf16rne(acc[nt][reg]);
            unsigned up = (unsigned)__shfl_xor((int)u, 1, 64);
            if (!(c & 1) && row >= 0)
                y[(size_t)row * 64 + (nt * 16 + c) / 2] = u | (up << 16);
        }
    }
}

// ---- agg1 (nodes [0,BS)) fused with linear+LayerNorm head -------------------
__global__ __launch_bounds__(256) void k_agg1head(
        const unsigned* __restrict__ xl,
        const int* __restrict__ cnt, const int* __restrict__ ssrc,
        const float* __restrict__ att, const float* __restrict__ bias,
        const float* __restrict__ wout, const float* __restrict__ bout,
        const float* __restrict__ gamma, const float* __restrict__ beta,
        float* __restrict__ yout, int N, int BS) {
    __shared__ float xrow[4][DD];
    int wid  = threadIdx.x >> 6;
    int lane = threadIdx.x & 63;
    int node = blockIdx.x * 4 + wid;
    if (node >= BS) return;
    float2 attv = *(const float2*)&att[lane * 2];
    float2 xd = bf2f(xl[(size_t)node * 64 + lane]);
    int key = N + node;
    int rs  = key * SLOT;
    int deg = cnt[key];
    deg = deg > SLOT ? SLOT : deg;

    float m = -3.4e38f, den = 0.f, accx = 0.f, accy = 0.f;
    int sA = (deg > 0) ? ssrc[rs] : 0;
    int sB = (deg > 1) ? ssrc[rs + 1] : 0;
    unsigned uA = xl[(size_t)sA * 64 + lane];
    unsigned uB = xl[(size_t)sB * 64 + lane];

    int k = 0;
    for (; k + 1 < deg; k += 2) {
        int sC = (k + 2 < deg) ? ssrc[rs + k + 2] : 0;
        int sD = (k + 3 < deg) ? ssrc[rs + k + 3] : 0;
        unsigned uC = xl[(size_t)sC * 64 + lane];
        unsigned uD = xl[(size_t)sD * 64 + lane];
        float2 vA = bf2f(uA), vB = bf2f(uB);
        float tx = xd.x + vA.x, ty = xd.y + vA.y;
        tx = tx > 0.f ? tx : 0.2f * tx;
        ty = ty > 0.f ? ty : 0.2f * ty;
        float l0 = tx * attv.x + ty * attv.y;
        tx = xd.x + vB.x; ty = xd.y + vB.y;
        tx = tx > 0.f ? tx : 0.2f * tx;
        ty = ty > 0.f ? ty : 0.2f * ty;
        float l1 = tx * attv.x + ty * attv.y;
        #pragma unroll
        for (int o = 8; o; o >>= 1) {
            l0 += __shfl_xor(l0, o, 64);
            l1 += __shfl_xor(l1, o, 64);
        }
        float mn = fmaxf(fmaxf(m, l0), l1);
        float corr = __expf(m - mn);
        float w0 = __expf(l0 - mn);
        float w1 = __expf(l1 - mn);
        den  = den  * corr + w0 + w1;
        accx = accx * corr + w0 * vA.x + w1 * vB.x;
        accy = accy * corr + w0 * vA.y + w1 * vB.y;
        m = mn;
        sA = sC; sB = sD; uA = uC; uB = uD;
    }
    if (k < deg) {
        float2 vA = bf2f(uA);
        float tx = xd.x + vA.x, ty = xd.y + vA.y;
        tx = tx > 0.f ? tx : 0.2f * tx;
        ty = ty > 0.f ? ty : 0.2f * ty;
        float l0 = tx * attv.x + ty * attv.y;
        #pragma unroll
        for (int o = 8; o; o >>= 1) l0 += __shfl_xor(l0, o, 64);
        float mn = fmaxf(m, l0);
        float corr = __expf(m - mn);
        float w0 = __expf(l0 - mn);
        den  = den  * corr + w0;
        accx = accx * corr + w0 * vA.x;
        accy = accy * corr + w0 * vA.y;
    }

    float inv = (deg > 0) ? 1.f / den : 0.f;
    float2 o2;
    o2.x = accx * inv + bias[lane * 2];
    o2.y = accy * inv + bias[lane * 2 + 1];

    xrow[wid][lane * 2]     = o2.x;
    xrow[wid][lane * 2 + 1] = o2.y;
    float2 acc2 = *(const float2*)&bout[lane * 2];
    __syncthreads();
    #pragma unroll 4
    for (int kk = 0; kk < DD; ++kk) {
        float xv = xrow[wid][kk];
        float2 wv2 = *(const float2*)&wout[(size_t)kk * DD + lane * 2];
        acc2.x += xv * wv2.x;
        acc2.y += xv * wv2.y;
    }
    float s = acc2.x + acc2.y;
    #pragma unroll
    for (int o = 32; o; o >>= 1) s += __shfl_xor(s, o, 64);
    float mean = s * (1.f / 128.f);
    float dx = acc2.x - mean, dy = acc2.y - mean;
    float s2 = dx * dx + dy * dy;
    #pragma unroll
    for (int o = 32; o; o >>= 1) s2 += __shfl_xor(s2, o, 64);
    float rstd = rsqrtf(s2 * (1.f / 128.f) + 1e-12f);
    float2 g2 = *(const float2*)&gamma[lane * 2];
    float2 b2 = *(const float2*)&beta[lane * 2];
    float2 yo;
    yo.x = dx * rstd * g2.x + b2.x;
    yo.y = dy * rstd * g2.y + b2.y;
    *(float2*)&yout[(size_t)node * DD + lane * 2] = yo;
}

extern "C" void kernel_launch(void* const* d_in, const int* in_sizes, int n_in,
                              void* d_out, int out_size, void* d_ws, size_t ws_size,
                              hipStream_t stream) {
    const float* embs  = (const float*)d_in[0];
    const float* w0    = (const float*)d_in[1];
    const float* b0    = (const float*)d_in[2];
    const float* att0  = (const float*)d_in[3];
    const float* bias0 = (const float*)d_in[4];
    const float* w1    = (const float*)d_in[5];
    const float* b1    = (const float*)d_in[6];
    const float* att1  = (const float*)d_in[7];
    const float* bias1 = (const float*)d_in[8];
    const float* wout  = (const float*)d_in[9];
    const float* bout  = (const float*)d_in[10];
    const float* gamma = (const float*)d_in[11];
    const float* beta  = (const float*)d_in[12];
    const int* ei0 = (const int*)d_in[13];
    const int* ei1 = (const int*)d_in[14];

    int N  = in_sizes[0] / DD;
    int E0 = in_sizes[13] / 2;
    int E1 = in_sizes[14] / 2;
    int BS = out_size / DD;
    int n2 = N + BS;
    int W  = (N + 31) / 32;

    // ---- workspace carve-up ----
    unsigned* xl   = (unsigned*)d_ws;                      // N*64 (bf16 pairs)
    unsigned* xg   = xl + (size_t)N * 64;                  // N*64 (bf16 pairs)
    int* ssrc      = (int*)(xg + (size_t)N * 64);          // n2*SLOT
    int* cnt       = ssrc + (size_t)n2 * SLOT;             // n2
    unsigned* mb   = (unsigned*)(cnt + n2);                // W+32
    int* nLive     = (int*)(mb + W + 32);                  // 1
    int* livelist  = nLive + 1;                            // N
    unsigned short* wp0 = (unsigned short*)
        (((uintptr_t)(livelist + N) + 15) & ~(uintptr_t)15); // 16K bf16
    unsigned short* wp1 = wp0 + DD * DD;                   // 16K bf16

    int gH0  = (E0 + 1023) / 1024;
    int gH1  = (E1 + 1023) / 1024;
    int gLin = (N + 63) / 64;
    int gZ   = 48;
    int Tz2  = BS + W + 32 + 1;   // cnt[N..n2) + mb + nLive (contiguous)

    // 1. tiny zero of conv1 cnt region + mb + nLive
    k_zero2<<<4, 256, 0, stream>>>(cnt + N, Tz2);
    // 2. mark: zero cnt[0..N) || conv1 hist/fill + livelist + w pack
    k_mark<<<gZ + gH1, 256, 0, stream>>>(ei1, ei1 + E1, E1, BS, mb, livelist,
                                         nLive, cnt, ssrc, N, w0, w1, wp0, wp1,
                                         gZ);
    // 3. F1: MFMA linear0 (loads-before-barrier) || conv0 hist+fill (filtered)
    k_hflin<<<gLin + gH0, 256, 0, stream>>>(
        embs, wp0, b0, xl, N, gLin, ei0, ei0 + E0, E0, mb, cnt, ssrc);
    // 4. agg0 (livelist-driven, 4-edge pipeline), epilogue gelu+pack -> xg
    k_aggL<<<(N + 3) / 4, 256, 0, stream>>>(xl, cnt, ssrc, att0, bias0, xg,
                                            livelist, nLive);
    // 5. lin1 over live rows (A-fragments direct from packed bf16 xg)
    k_linC<<<gLin, 256, 0, stream>>>(xg, wp1, b1, xl, livelist, nLive);
    // 6. agg1 (dst<BS) + head
    k_agg1head<<<(BS + 3) / 4, 256, 0, stream>>>(
        xl, cnt, ssrc, att1, bias1,
        wout, bout, gamma, beta, (float*)d_out, N, BS);
}

// Round 24
// 76.574 us; speedup vs baseline: 1.0215x; 1.0215x over previous
//
#include <hip/hip_runtime.h>
#include <math.h>

#define DD 128
#define SLOT 64   // fixed CSR bucket stride; deg~Poisson(12.8), P(>64) ~ 0

typedef short bf16x8 __attribute__((ext_vector_type(8)));
typedef float f32x4  __attribute__((ext_vector_type(4)));

__device__ __forceinline__ unsigned bf16rne(float f) {
    unsigned u = __float_as_uint(f);
    return (u + 0x7FFFu + ((u >> 16) & 1u)) >> 16;
}
__device__ __forceinline__ float2 bf2f(unsigned u) {
    float2 r;
    r.x = __uint_as_float(u << 16);
    r.y = __uint_as_float(u & 0xFFFF0000u);
    return r;
}
__device__ __forceinline__ float gelu1(float v) {
    return 0.5f * v * (1.f + erff(v * 0.70710678118654752f));
}

// ---- tiny zero: conv1 cnt region + mb + nLive (~2.7k ints) ------------------
__global__ __launch_bounds__(256) void k_zero2(int* __restrict__ p, int T) {
    int stride = gridDim.x * 256;
    for (int i = blockIdx.x * 256 + threadIdx.x; i < T; i += stride) p[i] = 0;
}

// ---- mark: [0,gZ) zero cnt[0..N) || conv1 hist/fill + livelist + w pack ----
__global__ __launch_bounds__(256) void k_mark(const int* __restrict__ src1,
                                              const int* __restrict__ dst1,
                                              int E1, int BS,
                                              unsigned* __restrict__ mb,
                                              int* __restrict__ livelist,
                                              int* __restrict__ nLive,
                                              int* __restrict__ cnt,
                                              int* __restrict__ ssrc, int N,
                                              const float* __restrict__ w0,
                                              const float* __restrict__ w1,
                                              unsigned short* __restrict__ wp0,
                                              unsigned short* __restrict__ wp1,
                                              int gZ) {
    if (blockIdx.x < gZ) {                    // zero cnt[0..N) for fill0
        int stride = gZ * 256;
        for (int i = blockIdx.x * 256 + threadIdx.x; i < N; i += stride)
            cnt[i] = 0;
        return;
    }
    __shared__ int lbuf[1280];
    __shared__ int lcnt, lbase;
    if (threadIdx.x == 0) lcnt = 0;
    __syncthreads();

    int role = blockIdx.x - gZ;
    int idx = role * 256 + threadIdx.x;
    if (idx < 2 * DD * DD) {
        const float* w = (idx < DD * DD) ? w0 : w1;
        unsigned short* wp = (idx < DD * DD) ? wp0 : wp1;
        int i = idx & (DD * DD - 1);
        int k = i >> 7, c = i & 127;
        int nt = c >> 4, ks = k >> 5;
        int lane = (c & 15) | (((k >> 3) & 3) << 4);
        wp[(((nt * 4 + ks) * 64) + lane) * 8 + (k & 7)] =
            (unsigned short)bf16rne(w[k * DD + c]);
    }

    int base = role * 1024 + threadIdx.x;
    #pragma unroll
    for (int j = 0; j < 4; ++j) {
        int e = base + j * 256;
        if (e < E1) {
            int d = dst1[e];
            if (d < BS) {
                int s = src1[e];
                int r = atomicAdd(&cnt[N + d], 1);
                if (r < SLOT) ssrc[(size_t)(N + d) * SLOT + r] = s;
                unsigned old = atomicOr(&mb[s >> 5], 1u << (s & 31));
                if (!((old >> (s & 31)) & 1u))
                    lbuf[atomicAdd(&lcnt, 1)] = s;
            }
        }
    }
    int g = role * 256 + threadIdx.x;
    if (g < BS) {
        unsigned old = atomicOr(&mb[g >> 5], 1u << (g & 31));
        if (!((old >> (g & 31)) & 1u))
            lbuf[atomicAdd(&lcnt, 1)] = g;
    }
    __syncthreads();
    if (threadIdx.x == 0) lbase = atomicAdd(nLive, lcnt);  // ONE global atomic
    __syncthreads();
    for (int i = threadIdx.x; i < lcnt; i += 256) livelist[lbase + i] = lbuf[i];
}

// ---- F1: MFMA linear0 (LDS weights, R15 body) || conv0 hist+fill -----------
__global__ __launch_bounds__(256) void k_hflin(
        const float* __restrict__ x, const unsigned short* __restrict__ wp,
        const float* __restrict__ b, unsigned* __restrict__ y, int nrows,
        int gLin,
        const int* __restrict__ src0, const int* __restrict__ dst0, int E0,
        const unsigned* __restrict__ mb, int* __restrict__ cnt,
        int* __restrict__ ssrc) {
    __shared__ bf16x8 wl[2048];   // 32 KB packed weights

    if (blockIdx.x >= gLin) {     // conv0 hist+fill (live dst only)
        int role = blockIdx.x - gLin;
        int base = role * 1024 + threadIdx.x;
        #pragma unroll
        for (int j = 0; j < 4; ++j) {
            int e = base + j * 256;
            if (e < E0) {
                int d = dst0[e];
                if ((mb[d >> 5] >> (d & 31)) & 1u) {
                    int r = atomicAdd(&cnt[d], 1);
                    if (r < SLOT) ssrc[(size_t)d * SLOT + r] = src0[e];
                }
            }
        }
        return;
    }

    const bf16x8* wg = (const bf16x8*)wp;
    #pragma unroll
    for (int i = 0; i < 8; ++i)
        wl[threadIdx.x + i * 256] = wg[threadIdx.x + i * 256];
    __syncthreads();

    int wave = threadIdx.x >> 6;
    int rb = blockIdx.x * 64 + wave * 16;
    int lane = threadIdx.x & 63;
    int c = lane & 15, g = lane >> 4;
    int rIn = rb + c;
    int rowValid = rIn < nrows;

    f32x4 acc[8];
    #pragma unroll
    for (int nt = 0; nt < 8; ++nt) {
        float bb = b[nt * 16 + c];
        acc[nt] = (f32x4){bb, bb, bb, bb};
    }
    for (int ks = 0; ks < 4; ++ks) {
        float xr[8];
        if (rowValid) {
            const float4* xp = (const float4*)&x[(size_t)rIn * DD + ks * 32 + g * 8];
            *(float4*)&xr[0] = xp[0];
            *(float4*)&xr[4] = xp[1];
        } else {
            #pragma unroll
            for (int j = 0; j < 8; ++j) xr[j] = 0.f;
        }
        union { unsigned u[4]; bf16x8 v; } af;
        #pragma unroll
        for (int j = 0; j < 4; ++j)
            af.u[j] = bf16rne(xr[2 * j]) | (bf16rne(xr[2 * j + 1]) << 16);
        #pragma unroll
        for (int nt = 0; nt < 8; ++nt)
            acc[nt] = __builtin_amdgcn_mfma_f32_16x16x32_bf16(
                af.v, wl[(nt * 4 + ks) * 64 + lane], acc[nt], 0, 0, 0);
    }
    int g4 = g * 4;
    #pragma unroll
    for (int nt = 0; nt < 8; ++nt) {
        #pragma unroll
        for (int reg = 0; reg < 4; ++reg) {
            unsigned u = bf16rne(acc[nt][reg]);
            unsigned up = (unsigned)__shfl_xor((int)u, 1, 64);
            int row = rb + g4 + reg;
            if (!(c & 1) && row < nrows)
                y[(size_t)row * 64 + (nt * 16 + c) / 2] = u | (up << 16);
        }
    }
}

// ---- agg0: livelist-driven, 4-edge pipeline; epilogue GELU+bf16 -> xg ------
__global__ __launch_bounds__(256) void k_aggL(const unsigned* __restrict__ xl,
                                              const int* __restrict__ cnt,
                                              const int* __restrict__ ssrc,
                                              const float* __restrict__ att,
                                              const float* __restrict__ bias,
                                              unsigned* __restrict__ xg,
                                              const int* __restrict__ livelist,
                                              const int* __restrict__ nLive) {
    int li = blockIdx.x * 4 + (threadIdx.x >> 6);
    if (li >= *nLive) return;
    int node = __builtin_amdgcn_readfirstlane(livelist[li]);
    int lane = threadIdx.x & 63;
    float2 attv = *(const float2*)&att[lane * 2];
    float2 xd = bf2f(xl[(size_t)node * 64 + lane]);
    int rs  = node * SLOT;
    int deg = cnt[node];
    deg = deg > SLOT ? SLOT : deg;

    float m = -3.4e38f, den = 0.f, accx = 0.f, accy = 0.f;
    int sA = (deg > 0) ? ssrc[rs]     : 0;
    int sB = (deg > 1) ? ssrc[rs + 1] : 0;
    int sC = (deg > 2) ? ssrc[rs + 2] : 0;
    int sD = (deg > 3) ? ssrc[rs + 3] : 0;
    unsigned uA = xl[(size_t)sA * 64 + lane];
    unsigned uB = xl[(size_t)sB * 64 + lane];
    unsigned uC = xl[(size_t)sC * 64 + lane];
    unsigned uD = xl[(size_t)sD * 64 + lane];

    int k = 0;
    for (; k + 3 < deg; k += 4) {
        int sE = (k + 4 < deg) ? ssrc[rs + k + 4] : 0;
        int sF = (k + 5 < deg) ? ssrc[rs + k + 5] : 0;
        int sG = (k + 6 < deg) ? ssrc[rs + k + 6] : 0;
        int sH = (k + 7 < deg) ? ssrc[rs + k + 7] : 0;
        unsigned uE = xl[(size_t)sE * 64 + lane];
        unsigned uF = xl[(size_t)sF * 64 + lane];
        unsigned uG = xl[(size_t)sG * 64 + lane];
        unsigned uH = xl[(size_t)sH * 64 + lane];
        float2 vA = bf2f(uA), vB = bf2f(uB), vC = bf2f(uC), vD = bf2f(uD);

        float t0x = xd.x + vA.x, t0y = xd.y + vA.y;
        t0x = t0x > 0.f ? t0x : 0.2f * t0x;
        t0y = t0y > 0.f ? t0y : 0.2f * t0y;
        float l0 = t0x * attv.x + t0y * attv.y;
        float t1x = xd.x + vB.x, t1y = xd.y + vB.y;
        t1x = t1x > 0.f ? t1x : 0.2f * t1x;
        t1y = t1y > 0.f ? t1y : 0.2f * t1y;
        float l1 = t1x * attv.x + t1y * attv.y;
        float t2x = xd.x + vC.x, t2y = xd.y + vC.y;
        t2x = t2x > 0.f ? t2x : 0.2f * t2x;
        t2y = t2y > 0.f ? t2y : 0.2f * t2y;
        float l2 = t2x * attv.x + t2y * attv.y;
        float t3x = xd.x + vD.x, t3y = xd.y + vD.y;
        t3x = t3x > 0.f ? t3x : 0.2f * t3x;
        t3y = t3y > 0.f ? t3y : 0.2f * t3y;
        float l3 = t3x * attv.x + t3y * attv.y;
        #pragma unroll
        for (int o = 8; o; o >>= 1) {
            l0 += __shfl_xor(l0, o, 64);
            l1 += __shfl_xor(l1, o, 64);
            l2 += __shfl_xor(l2, o, 64);
            l3 += __shfl_xor(l3, o, 64);
        }
        float mn = fmaxf(fmaxf(fmaxf(m, l0), fmaxf(l1, l2)), l3);
        float corr = __expf(m - mn);
        float w0 = __expf(l0 - mn);
        float w1 = __expf(l1 - mn);
        float w2 = __expf(l2 - mn);
        float w3 = __expf(l3 - mn);
        den  = den  * corr + w0 + w1 + w2 + w3;
        accx = accx * corr + w0 * vA.x + w1 * vB.x + w2 * vC.x + w3 * vD.x;
        accy = accy * corr + w0 * vA.y + w1 * vB.y + w2 * vC.y + w3 * vD.y;
        m = mn;
        sA = sE; sB = sF; sC = sG; sD = sH;
        uA = uE; uB = uF; uC = uG; uD = uH;
    }
    for (; k < deg; ++k) {      // 0-3 tail edges, rotate through uA
        float2 vA = bf2f(uA);
        float tx = xd.x + vA.x, ty = xd.y + vA.y;
        tx = tx > 0.f ? tx : 0.2f * tx;
        ty = ty > 0.f ? ty : 0.2f * ty;
        float l0 = tx * attv.x + ty * attv.y;
        #pragma unroll
        for (int o = 8; o; o >>= 1) l0 += __shfl_xor(l0, o, 64);
        float mn = fmaxf(m, l0);
        float corr = __expf(m - mn);
        float w0 = __expf(l0 - mn);
        den  = den  * corr + w0;
        accx = accx * corr + w0 * vA.x;
        accy = accy * corr + w0 * vA.y;
        m = mn;
        uA = uB; uB = uC; uC = uD;
    }

    float inv = (deg > 0) ? 1.f / den : 0.f;
    float gx = gelu1(accx * inv + bias[lane * 2]);
    float gy = gelu1(accy * inv + bias[lane * 2 + 1]);
    xg[(size_t)node * 64 + lane] = bf16rne(gx) | (bf16rne(gy) << 16);
}

// ---- lin1 over livelist rows: MFMA, A-fragments loaded as packed bf16 ------
__global__ __launch_bounds__(256) void k_linC(const unsigned* __restrict__ xg,
                                              const unsigned short* __restrict__ wp,
                                              const float* __restrict__ b,
                                              unsigned* __restrict__ y,
                                              const int* __restrict__ livelist,
                                              const int* __restrict__ nLive) {
    __shared__ bf16x8 wl[2048];   // 32 KB
    int nL = *nLive;
    if (blockIdx.x * 64 >= nL) return;

    const bf16x8* wg = (const bf16x8*)wp;
    #pragma unroll
    for (int i = 0; i < 8; ++i)
        wl[threadIdx.x + i * 256] = wg[threadIdx.x + i * 256];
    __syncthreads();

    int wave = threadIdx.x >> 6;
    int lb = blockIdx.x * 64 + wave * 16;
    int lane = threadIdx.x & 63;
    int c = lane & 15, g = lane >> 4;
    int liIn = lb + c;
    int rIn = (liIn < nL) ? livelist[liIn] : 0;
    const uint4* xp = (const uint4*)&xg[(size_t)rIn * 64];

    f32x4 acc[8];
    #pragma unroll
    for (int nt = 0; nt < 8; ++nt) {
        float bb = b[nt * 16 + c];
        acc[nt] = (f32x4){bb, bb, bb, bb};
    }
    #pragma unroll
    for (int ks = 0; ks < 4; ++ks) {
        union { uint4 q; bf16x8 v; } af;
        if (liIn < nL) af.q = xp[ks * 4 + g];
        else           af.q = make_uint4(0, 0, 0, 0);
        #pragma unroll
        for (int nt = 0; nt < 8; ++nt)
            acc[nt] = __builtin_amdgcn_mfma_f32_16x16x32_bf16(
                af.v, wl[(nt * 4 + ks) * 64 + lane], acc[nt], 0, 0, 0);
    }
    int g4 = g * 4;
    #pragma unroll
    for (int reg = 0; reg < 4; ++reg) {
        int liOut = lb + g4 + reg;
        int row = (liOut < nL) ? livelist[liOut] : -1;
        #pragma unroll
        for (int nt = 0; nt < 8; ++nt) {
            unsigned u = bf16rne(acc[nt][reg]);
            unsigned up = (unsigned)__shfl_xor((int)u, 1, 64);
            if (!(c & 1) && row >= 0)
                y[(size_t)row * 64 + (nt * 16 + c) / 2] = u | (up << 16);
        }
    }
}

// ---- agg1 (nodes [0,BS)) fused with linear+LayerNorm head -------------------
__global__ __launch_bounds__(256) void k_agg1head(
        const unsigned* __restrict__ xl,
        const int* __restrict__ cnt, const int* __restrict__ ssrc,
        const float* __restrict__ att, const float* __restrict__ bias,
        const float* __restrict__ wout, const float* __restrict__ bout,
        const float* __restrict__ gamma, const float* __restrict__ beta,
        float* __restrict__ yout, int N, int BS) {
    __shared__ float xrow[4][DD];
    int wid  = threadIdx.x >> 6;
    int lane = threadIdx.x & 63;
    int node = blockIdx.x * 4 + wid;
    if (node >= BS) return;
    float2 attv = *(const float2*)&att[lane * 2];
    float2 xd = bf2f(xl[(size_t)node * 64 + lane]);
    int key = N + node;
    int rs  = key * SLOT;
    int deg = cnt[key];
    deg = deg > SLOT ? SLOT : deg;

    float m = -3.4e38f, den = 0.f, accx = 0.f, accy = 0.f;
    int sA = (deg > 0) ? ssrc[rs] : 0;
    int sB = (deg > 1) ? ssrc[rs + 1] : 0;
    unsigned uA = xl[(size_t)sA * 64 + lane];
    unsigned uB = xl[(size_t)sB * 64 + lane];

    int k = 0;
    for (; k + 1 < deg; k += 2) {
        int sC = (k + 2 < deg) ? ssrc[rs + k + 2] : 0;
        int sD = (k + 3 < deg) ? ssrc[rs + k + 3] : 0;
        unsigned uC = xl[(size_t)sC * 64 + lane];
        unsigned uD = xl[(size_t)sD * 64 + lane];
        float2 vA = bf2f(uA), vB = bf2f(uB);
        float tx = xd.x + vA.x, ty = xd.y + vA.y;
        tx = tx > 0.f ? tx : 0.2f * tx;
        ty = ty > 0.f ? ty : 0.2f * ty;
        float l0 = tx * attv.x + ty * attv.y;
        tx = xd.x + vB.x; ty = xd.y + vB.y;
        tx = tx > 0.f ? tx : 0.2f * tx;
        ty = ty > 0.f ? ty : 0.2f * ty;
        float l1 = tx * attv.x + ty * attv.y;
        #pragma unroll
        for (int o = 8; o; o >>= 1) {
            l0 += __shfl_xor(l0, o, 64);
            l1 += __shfl_xor(l1, o, 64);
        }
        float mn = fmaxf(fmaxf(m, l0), l1);
        float corr = __expf(m - mn);
        float w0 = __expf(l0 - mn);
        float w1 = __expf(l1 - mn);
        den  = den  * corr + w0 + w1;
        accx = accx * corr + w0 * vA.x + w1 * vB.x;
        accy = accy * corr + w0 * vA.y + w1 * vB.y;
        m = mn;
        sA = sC; sB = sD; uA = uC; uB = uD;
    }
    if (k < deg) {
        float2 vA = bf2f(uA);
        float tx = xd.x + vA.x, ty = xd.y + vA.y;
        tx = tx > 0.f ? tx : 0.2f * tx;
        ty = ty > 0.f ? ty : 0.2f * ty;
        float l0 = tx * attv.x + ty * attv.y;
        #pragma unroll
        for (int o = 8; o; o >>= 1) l0 += __shfl_xor(l0, o, 64);
        float mn = fmaxf(m, l0);
        float corr = __expf(m - mn);
        float w0 = __expf(l0 - mn);
        den  = den  * corr + w0;
        accx = accx * corr + w0 * vA.x;
        accy = accy * corr + w0 * vA.y;
    }

    float inv = (deg > 0) ? 1.f / den : 0.f;
    float2 o2;
    o2.x = accx * inv + bias[lane * 2];
    o2.y = accy * inv + bias[lane * 2 + 1];

    xrow[wid][lane * 2]     = o2.x;
    xrow[wid][lane * 2 + 1] = o2.y;
    float2 acc2 = *(const float2*)&bout[lane * 2];
    __syncthreads();
    #pragma unroll 4
    for (int kk = 0; kk < DD; ++kk) {
        float xv = xrow[wid][kk];
        float2 wv2 = *(const float2*)&wout[(size_t)kk * DD + lane * 2];
        acc2.x += xv * wv2.x;
        acc2.y += xv * wv2.y;
    }
    float s = acc2.x + acc2.y;
    #pragma unroll
    for (int o = 32; o; o >>= 1) s += __shfl_xor(s, o, 64);
    float mean = s * (1.f / 128.f);
    float dx = acc2.x - mean, dy = acc2.y - mean;
    float s2 = dx * dx + dy * dy;
    #pragma unroll
    for (int o = 32; o; o >>= 1) s2 += __shfl_xor(s2, o, 64);
    float rstd = rsqrtf(s2 * (1.f / 128.f) + 1e-12f);
    float2 g2 = *(const float2*)&gamma[lane * 2];
    float2 b2 = *(const float2*)&beta[lane * 2];
    float2 yo;
    yo.x = dx * rstd * g2.x + b2.x;
    yo.y = dy * rstd * g2.y + b2.y;
    *(float2*)&yout[(size_t)node * DD + lane * 2] = yo;
}

extern "C" void kernel_launch(void* const* d_in, const int* in_sizes, int n_in,
                              void* d_out, int out_size, void* d_ws, size_t ws_size,
                              hipStream_t stream) {
    const float* embs  = (const float*)d_in[0];
    const float* w0    = (const float*)d_in[1];
    const float* b0    = (const float*)d_in[2];
    const float* att0  = (const float*)d_in[3];
    const float* bias0 = (const float*)d_in[4];
    const float* w1    = (const float*)d_in[5];
    const float* b1    = (const float*)d_in[6];
    const float* att1  = (const float*)d_in[7];
    const float* bias1 = (const float*)d_in[8];
    const float* wout  = (const float*)d_in[9];
    const float* bout  = (const float*)d_in[10];
    const float* gamma = (const float*)d_in[11];
    const float* beta  = (const float*)d_in[12];
    const int* ei0 = (const int*)d_in[13];
    const int* ei1 = (const int*)d_in[14];

    int N  = in_sizes[0] / DD;
    int E0 = in_sizes[13] / 2;
    int E1 = in_sizes[14] / 2;
    int BS = out_size / DD;
    int n2 = N + BS;
    int W  = (N + 31) / 32;

    // ---- workspace carve-up ----
    unsigned* xl   = (unsigned*)d_ws;                      // N*64 (bf16 pairs)
    unsigned* xg   = xl + (size_t)N * 64;                  // N*64 (bf16 pairs)
    int* ssrc      = (int*)(xg + (size_t)N * 64);          // n2*SLOT
    int* cnt       = ssrc + (size_t)n2 * SLOT;             // n2
    unsigned* mb   = (unsigned*)(cnt + n2);                // W+32
    int* nLive     = (int*)(mb + W + 32);                  // 1
    int* livelist  = nLive + 1;                            // N
    unsigned short* wp0 = (unsigned short*)
        (((uintptr_t)(livelist + N) + 15) & ~(uintptr_t)15); // 16K bf16
    unsigned short* wp1 = wp0 + DD * DD;                   // 16K bf16

    int gH0  = (E0 + 1023) / 1024;
    int gH1  = (E1 + 1023) / 1024;
    int gLin = (N + 63) / 64;
    int gZ   = 48;
    int Tz2  = BS + W + 32 + 1;   // cnt[N..n2) + mb + nLive (contiguous)

    // 1. tiny zero of conv1 cnt region + mb + nLive
    k_zero2<<<4, 256, 0, stream>>>(cnt + N, Tz2);
    // 2. mark: zero cnt[0..N) || conv1 hist/fill + livelist + w pack
    k_mark<<<gZ + gH1, 256, 0, stream>>>(ei1, ei1 + E1, E1, BS, mb, livelist,
                                         nLive, cnt, ssrc, N, w0, w1, wp0, wp1,
                                         gZ);
    // 3. F1: MFMA linear0 || conv0 hist+fill (filtered)
    k_hflin<<<gLin + gH0, 256, 0, stream>>>(
        embs, wp0, b0, xl, N, gLin, ei0, ei0 + E0, E0, mb, cnt, ssrc);
    // 4. agg0 (livelist-driven, 4-edge pipeline), epilogue gelu+pack -> xg
    k_aggL<<<(N + 3) / 4, 256, 0, stream>>>(xl, cnt, ssrc, att0, bias0, xg,
                                            livelist, nLive);
    // 5. lin1 over live rows (A-fragments direct from packed bf16 xg)
    k_linC<<<gLin, 256, 0, stream>>>(xg, wp1, b1, xl, livelist, nLive);
    // 6. agg1 (dst<BS) + head
    k_agg1head<<<(BS + 3) / 4, 256, 0, stream>>>(
        xl, cnt, ssrc, att1, bias1,
        wout, bout, gamma, beta, (float*)d_out, N, BS);
}